// Round 2
// baseline (567.956 us; speedup 1.0000x reference)
//
#include <hip/hip_runtime.h>

// (B,C,L,H,W) = (4,64,16,32,32), K=1024, D=C=64
constexpr int Cc   = 64;
constexpr int Lc   = 16;
constexpr int Hc   = 32;
constexpr int Wc   = 32;
constexpr int Kc   = 1024;
constexpr int Dc   = 64;
constexpr int LHWc = Lc * Hc * Wc;        // 16384
constexpr int Nc   = 4 * LHWc;            // 65536 vectors
constexpr int QSIZE    = 4 * Cc * LHWc;   // 4194304
constexpr int OFF_LOSS = QSIZE;           // 4194304
constexpr int OFF_IDX  = QSIZE + 1;       // 4194305

__global__ void vq_zero(float* __restrict__ out) {
    out[OFF_LOSS] = 0.0f;
}

// Force a pointer into SGPRs so dependent loads can select s_load.
__device__ __forceinline__ const float* uniform_ptr(const float* p) {
    unsigned long long u = (unsigned long long)p;
    unsigned lo = __builtin_amdgcn_readfirstlane((unsigned)u);
    unsigned hi = __builtin_amdgcn_readfirstlane((unsigned)(u >> 32));
    return (const float*)(((unsigned long long)hi << 32) | lo);
}

__global__ __launch_bounds__(256) void vq_main(
    const float* __restrict__ in, const float* __restrict__ codebook,
    float* __restrict__ out)
{
    __shared__ float c2s[Kc];                 // ||c_k||^2, block-wide
    __shared__ unsigned long long red[256];   // per-wave argmin candidates

    const int tid  = threadIdx.x;
    const int lane = tid & 63;
    const int wave = __builtin_amdgcn_readfirstlane(tid >> 6);
    const int k0   = wave * 256;              // this wave's code range

    // ---- per-wave c2 fill (lane computes 4 rows), identical fma chain as the
    // validated round-1 numerics ----
#pragma unroll
    for (int j = 0; j < 4; ++j) {
        const int k = k0 + lane * 4 + j;
        const float* c = codebook + (size_t)k * Dc;
        float s = 0.f;
#pragma unroll
        for (int d = 0; d < Dc; ++d) s = __builtin_fmaf(c[d], c[d], s);
        c2s[k] = s;
    }
    __syncthreads();

    const int n = blockIdx.x * 64 + lane;     // vector id
    const int b = n >> 14;                    // LHW = 2^14
    const int p = n & (LHWc - 1);

    const float* xin = in + (size_t)b * (Cc * LHWc) + p;

    // x into registers (coalesced across lanes per channel)
    float x[Dc];
#pragma unroll
    for (int d = 0; d < Dc; ++d) x[d] = xin[(size_t)d * LHWc];

    float x2 = 0.f;
#pragma unroll
    for (int d = 0; d < Dc; ++d) x2 = __builtin_fmaf(x[d], x[d], x2);

    unsigned long long best = ~0ull;
    for (int kk = 0; kk < 256; kk += 2) {
        const int ka = k0 + kk;
        const int kb = ka + 1;
        const float* ca = uniform_ptr(codebook + (size_t)ka * Dc);
        const float* cbp = uniform_ptr(codebook + (size_t)kb * Dc);
        float a0 = 0.f, a1 = 0.f;
#pragma unroll
        for (int d = 0; d < Dc; ++d) {
            a0 = __builtin_fmaf(x[d], ca[d], a0);   // exact sequential order
            a1 = __builtin_fmaf(x[d], cbp[d], a1);  // independent chain (ILP)
        }
        // reference rounding: d2 = fl(fl(x2 - fl(2*dot)) + c2)
        float t0  = __builtin_fmaf(-2.0f, a0, x2);
        float d20 = t0 + c2s[ka];
        float t1  = __builtin_fmaf(-2.0f, a1, x2);
        float d21 = t1 + c2s[kb];
        // d2 > 0 here, so float bits are order-preserving as uint
        unsigned long long p0 =
            ((unsigned long long)__float_as_uint(d20) << 32) | (unsigned)ka;
        unsigned long long p1 =
            ((unsigned long long)__float_as_uint(d21) << 32) | (unsigned)kb;
        best = p0 < best ? p0 : best;
        best = p1 < best ? p1 : best;
    }

    red[wave * 64 + lane] = best;
    __syncthreads();

    if (wave == 0) {
        unsigned long long bb = red[lane];
#pragma unroll
        for (int w = 1; w < 4; ++w) {
            unsigned long long o = red[w * 64 + lane];
            bb = o < bb ? o : bb;             // u64 min: ties -> lowest k (k in low bits)
        }
        const int k = (int)(bb & 0xffffffffu);

        out[OFF_IDX + n] = (float)k;

        const float* ck = codebook + (size_t)k * Dc;
        float* qout = out + (size_t)b * (Cc * LHWc) + p;
        float lsum = 0.f;
#pragma unroll
        for (int c = 0; c < Dc; ++c) {
            float q = ck[c];
            qout[(size_t)c * LHWc] = q;       // coalesced across lanes per c
            float e = q - x[c];
            lsum = __builtin_fmaf(e, e, lsum);
        }
#pragma unroll
        for (int off = 32; off > 0; off >>= 1)
            lsum += __shfl_down(lsum, off, 64);
        if (lane == 0)
            atomicAdd(&out[OFF_LOSS], lsum * (1.25f / (float)QSIZE));
    }
}

extern "C" void kernel_launch(void* const* d_in, const int* in_sizes, int n_in,
                              void* d_out, int out_size, void* d_ws, size_t ws_size,
                              hipStream_t stream) {
    const float* in = (const float*)d_in[0];   // [4,64,16,32,32] f32
    const float* cb = (const float*)d_in[1];   // [1024,64] f32
    float* out = (float*)d_out;
    (void)d_ws; (void)ws_size;                 // d_ws intentionally unused

    vq_zero<<<dim3(1), dim3(1), 0, stream>>>(out);
    vq_main<<<dim3(Nc / 64), dim3(256), 0, stream>>>(in, cb, out);
}

// Round 3
// 236.111 us; speedup vs baseline: 2.4055x; 2.4055x over previous
//
#include <hip/hip_runtime.h>

// (B,C,L,H,W) = (4,64,16,32,32), K=1024, D=C=64
constexpr int Cc   = 64;
constexpr int Kc   = 1024;
constexpr int Dc   = 64;
constexpr int LHWc = 16 * 32 * 32;        // 16384
constexpr int Nc   = 4 * LHWc;            // 65536 vectors
constexpr int QSIZE    = 4 * Cc * LHWc;   // 4194304
constexpr int OFF_LOSS = QSIZE;           // 4194304
constexpr int OFF_IDX  = QSIZE + 1;       // 4194305

constexpr int WAVES  = 8;                 // waves per block
constexpr int KPW    = Kc / WAVES;        // 128 codes per wave

typedef __attribute__((ext_vector_type(16))) float f16v;

__global__ void vq_zero(float* __restrict__ out) {
    out[OFF_LOSS] = 0.0f;
}

__global__ __launch_bounds__(WAVES * 64) void vq_main(
    const float* __restrict__ in, const float* __restrict__ codebook,
    float* __restrict__ out)
{
    __shared__ float c2s[Kc];                    // ||c_k||^2
    __shared__ unsigned long long red[WAVES * 64];

    const int tid  = threadIdx.x;
    const int lane = tid & 63;
    const int wave = __builtin_amdgcn_readfirstlane(tid >> 6);
    const int k0   = wave * KPW;                 // this wave's code range

    // c2 fill: 512 threads x 2 codes, exact fma chain (same numerics as r2)
#pragma unroll
    for (int j = 0; j < 2; ++j) {
        const int k = tid * 2 + j;
        const float* c = codebook + (size_t)k * Dc;
        float s = 0.f;
#pragma unroll
        for (int d = 0; d < Dc; ++d) s = __builtin_fmaf(c[d], c[d], s);
        c2s[k] = s;
    }
    __syncthreads();

    const int n = blockIdx.x * 64 + lane;        // vector id
    const int b = n >> 14;                       // LHW = 2^14
    const int p = n & (LHWc - 1);

    const float* xin = in + (size_t)b * (Cc * LHWc) + p;

    float x[Dc];
#pragma unroll
    for (int d = 0; d < Dc; ++d) x[d] = xin[(size_t)d * LHWc];

    float x2 = 0.f;
#pragma unroll
    for (int d = 0; d < Dc; ++d) x2 = __builtin_fmaf(x[d], x[d], x2);

    unsigned long long best = ~0ull;
#pragma unroll 1
    for (int kk = 0; kk < KPW; ++kk) {
        const int k = k0 + kk;                   // wave-uniform
        const float* ckp = codebook + (size_t)k * Dc;
        f16v c0, c1, c2v, c3;
        // Force the broadcast codebook row through the scalar pipe:
        // 4 back-to-back s_load_dwordx16 (one L2 round-trip), one wait.
        asm volatile(
            "s_load_dwordx16 %0, %4, 0x0\n\t"
            "s_load_dwordx16 %1, %4, 0x40\n\t"
            "s_load_dwordx16 %2, %4, 0x80\n\t"
            "s_load_dwordx16 %3, %4, 0xc0\n\t"
            "s_waitcnt lgkmcnt(0)"
            : "=s"(c0), "=s"(c1), "=s"(c2v), "=s"(c3)
            : "s"(ckp));

        // exact sequential fma chain over d = 0..63 (bit-identical to r2)
        float acc = 0.f;
#pragma unroll
        for (int j = 0; j < 16; ++j) acc = __builtin_fmaf(x[j],      c0[j], acc);
#pragma unroll
        for (int j = 0; j < 16; ++j) acc = __builtin_fmaf(x[16 + j], c1[j], acc);
#pragma unroll
        for (int j = 0; j < 16; ++j) acc = __builtin_fmaf(x[32 + j], c2v[j], acc);
#pragma unroll
        for (int j = 0; j < 16; ++j) acc = __builtin_fmaf(x[48 + j], c3[j], acc);

        // reference rounding: d2 = fl(fl(x2 - fl(2*dot)) + c2)
        float t  = __builtin_fmaf(-2.0f, acc, x2);
        float d2 = t + c2s[k];
        // d2 > 0 -> float bits order-preserving as uint
        unsigned long long pk =
            ((unsigned long long)__float_as_uint(d2) << 32) | (unsigned)k;
        best = pk < best ? pk : best;            // strict < keeps lowest k on ties
    }

    red[wave * 64 + lane] = best;
    __syncthreads();

    if (wave == 0) {
        unsigned long long bb = red[lane];
#pragma unroll
        for (int w = 1; w < WAVES; ++w) {
            unsigned long long o = red[w * 64 + lane];
            bb = o < bb ? o : bb;                // wave order == k order
        }
        const int k = (int)(bb & 0xffffffffu);

        out[OFF_IDX + n] = (float)k;

        const float* ck = codebook + (size_t)k * Dc;
        float* qout = out + (size_t)b * (Cc * LHWc) + p;
        float lsum = 0.f;
#pragma unroll
        for (int c = 0; c < Dc; ++c) {
            float q = ck[c];
            qout[(size_t)c * LHWc] = q;          // coalesced across lanes per c
            float e = q - x[c];
            lsum = __builtin_fmaf(e, e, lsum);
        }
#pragma unroll
        for (int off = 32; off > 0; off >>= 1)
            lsum += __shfl_down(lsum, off, 64);
        if (lane == 0)
            atomicAdd(&out[OFF_LOSS], lsum * (1.25f / (float)QSIZE));
    }
}

extern "C" void kernel_launch(void* const* d_in, const int* in_sizes, int n_in,
                              void* d_out, int out_size, void* d_ws, size_t ws_size,
                              hipStream_t stream) {
    const float* in = (const float*)d_in[0];   // [4,64,16,32,32] f32
    const float* cb = (const float*)d_in[1];   // [1024,64] f32
    float* out = (float*)d_out;
    (void)d_ws; (void)ws_size;

    vq_zero<<<dim3(1), dim3(1), 0, stream>>>(out);
    vq_main<<<dim3(Nc / 64), dim3(WAVES * 64), 0, stream>>>(in, cb, out);
}